// Round 4
// baseline (2691.992 us; speedup 1.0000x reference)
//
#include <hip/hip_runtime.h>
#include <cstddef>
#include <cstdint>

#define NSAMP 256
#define NTT   512
#define NXX   512

typedef _Float16 h4 __attribute__((ext_vector_type(4)));
typedef _Float16 h8 __attribute__((ext_vector_type(8)));
typedef float    f4 __attribute__((ext_vector_type(4)));

typedef const __attribute__((address_space(1))) unsigned int* gptr_t;
typedef __attribute__((address_space(3))) unsigned int*       lptr_t;

__device__ __forceinline__ void gload_lds16(const void* g, void* l) {
    __builtin_amdgcn_global_load_lds((gptr_t)g, (lptr_t)l, 16, 0, 0);
}

// ---------------------------------------------------------------------------
// Kernel 1: per-sample T0 (argmin |phi[b,:,0]| and |phi[b,:,1]|, first-index
// ties, then T0 = (t0 > t1) ? t1 : t0 per reference).
// ---------------------------------------------------------------------------
__global__ __launch_bounds__(64)
void k_t0(const float* __restrict__ phi, int* __restrict__ T0) {
    const int b = blockIdx.x;
    const float* p = phi + (size_t)b * NTT * NXX;
    const int lane = threadIdx.x;

    float b0 = 1e30f, b1 = 1e30f;
    int i0 = 0, i1 = 0;
    for (int t = lane; t < NTT; t += 64) {
        float2 v = *reinterpret_cast<const float2*>(p + (size_t)t * NXX);
        float a0 = fabsf(v.x), a1 = fabsf(v.y);
        if (a0 < b0) { b0 = a0; i0 = t; }
        if (a1 < b1) { b1 = a1; i1 = t; }
    }
    #pragma unroll
    for (int off = 32; off > 0; off >>= 1) {
        float o0 = __shfl_down(b0, off); int oi0 = __shfl_down(i0, off);
        float o1 = __shfl_down(b1, off); int oi1 = __shfl_down(i1, off);
        if (o0 < b0 || (o0 == b0 && oi0 < i0)) { b0 = o0; i0 = oi0; }
        if (o1 < b1 || (o1 == b1 && oi1 < i1)) { b1 = o1; i1 = oi1; }
    }
    if (lane == 0) T0[b] = (i0 > i1) ? i1 : i0;
}

// ---------------------------------------------------------------------------
// Kernel 2: build shift-replicated transposed split-f16 W tables:
//   Wtd_{hi,lo}[s][y][u] = split(W[(u+s)&511][y]),  s in 0..7, u in 0..511.
// B-tile k-origin (T0 = 8q + s) is then 16B-aligned in table s, with chunk
// starts wrapped mod 512 at 8-element granularity (start <= 504, so every
// 16B chunk is in-bounds).
// ---------------------------------------------------------------------------
__global__ __launch_bounds__(256)
void k_prep(const float* __restrict__ W, _Float16* __restrict__ Whi,
            _Float16* __restrict__ Wlo) {
    __shared__ float colf[NXX];
    const int y = blockIdx.x;
    const int tid = threadIdx.x;
    for (int r = tid; r < NXX; r += 256) colf[r] = W[(size_t)r * NXX + y];
    __syncthreads();
    const int u0 = (tid & 127) * 4;        // 128 float4 groups cover u=512
    const int sb = tid >> 7;               // two shift-streams in parallel
    #pragma unroll
    for (int si = 0; si < 4; ++si) {
        const int sh = sb + 2 * si;
        h4 hv, lv;
        #pragma unroll
        for (int j = 0; j < 4; ++j) {
            float x = colf[(u0 + j + sh) & (NXX - 1)];
            _Float16 h = (_Float16)x;
            _Float16 l = (_Float16)(x - (float)h);
            hv[j] = h; lv[j] = l;
        }
        size_t idx = ((size_t)(sh * NXX + y)) * 512 + u0;
        *(h4*)(Whi + idx) = hv;
        *(h4*)(Wlo + idx) = lv;
    }
}

// ---------------------------------------------------------------------------
// Kernel 3: block 0 = LU logabsdet(W); blocks 1..4096 = fused MFMA GEMM.
//   out[b,(t-T0)%Nt,y] = sum_x phi[b,t,x] * W[(x+T0)%Nx,y]
// GEMM: 128x128 tile, BK=32, 4 waves (each 64x64 = 4x4 fragments of 16x16),
// split-fp16 3-product MFMA (hi*hi + hi*lo + lo*hi), B staged via
// global_load_lds from the Wtd tables, output roll = row-permuted store.
// ---------------------------------------------------------------------------
#define LDS_BYTES 36864

__global__ __launch_bounds__(256)
void k_main(const float* __restrict__ phi,
            const _Float16* __restrict__ Whi, const _Float16* __restrict__ Wlo,
            const int* __restrict__ T0, float* __restrict__ out,
            float* __restrict__ logdet, const float* __restrict__ W,
            float* __restrict__ M) {
    __shared__ __align__(16) char smem_raw[LDS_BYTES];
    __shared__ int   s_piv[16];
    __shared__ float s_redv[4];
    __shared__ int   s_redi[4];
    __shared__ float s_logsum;

    const int tid = threadIdx.x;

    if (blockIdx.x == 0) {
        // ================= LU path (one block): logabsdet(W) ================
        float* P = (float*)smem_raw;  // [512][17] = 34816 B

        for (int i = tid; i < (NXX * NXX) / 4; i += 256)
            reinterpret_cast<float4*>(M)[i] =
                reinterpret_cast<const float4*>(W)[i];
        __syncthreads();

        float logsum = 0.0f;

        for (int p = 0; p < NXX / 16; ++p) {
            const int k0 = p * 16;
            const int m  = NXX - k0;

            for (int idx = tid; idx < m * 16; idx += 256) {
                int r = idx >> 4, c = idx & 15;
                P[r * 17 + c] = M[(size_t)(k0 + r) * NXX + k0 + c];
            }
            __syncthreads();

            for (int j = 0; j < 16; ++j) {
                float bv = -1.0f; int bi = j;
                for (int i = j + tid; i < m; i += 256) {
                    float v = fabsf(P[i * 17 + j]);
                    if (v > bv) { bv = v; bi = i; }
                }
                #pragma unroll
                for (int off = 32; off > 0; off >>= 1) {
                    float ov = __shfl_down(bv, off); int oi = __shfl_down(bi, off);
                    if (ov > bv || (ov == bv && oi < bi)) { bv = ov; bi = oi; }
                }
                if ((tid & 63) == 0) { s_redv[tid >> 6] = bv; s_redi[tid >> 6] = bi; }
                __syncthreads();
                if (tid == 0) {
                    bv = s_redv[0]; bi = s_redi[0];
                    for (int qq = 1; qq < 4; ++qq)
                        if (s_redv[qq] > bv || (s_redv[qq] == bv && s_redi[qq] < bi)) {
                            bv = s_redv[qq]; bi = s_redi[qq];
                        }
                    s_piv[j] = bi;
                }
                __syncthreads();
                const int piv = s_piv[j];
                if (piv != j && tid < 16) {
                    float tmp = P[j * 17 + tid];
                    P[j * 17 + tid]   = P[piv * 17 + tid];
                    P[piv * 17 + tid] = tmp;
                }
                __syncthreads();
                const float d = P[j * 17 + j];
                if (tid == 0) logsum += logf(fabsf(d));
                for (int i = j + 1 + tid; i < m; i += 256) {
                    float lij = P[i * 17 + j] / d;
                    P[i * 17 + j] = lij;
                    for (int c = j + 1; c < 16; ++c)
                        P[i * 17 + c] -= lij * P[j * 17 + c];
                }
                __syncthreads();
            }

            for (int j = 0; j < 16; ++j) {
                const int piv = s_piv[j];
                if (piv != j) {
                    const int ra = k0 + j, rb = k0 + piv;
                    for (int c = k0 + 16 + tid; c < NXX; c += 256) {
                        float ta = M[(size_t)ra * NXX + c];
                        M[(size_t)ra * NXX + c] = M[(size_t)rb * NXX + c];
                        M[(size_t)rb * NXX + c] = ta;
                    }
                }
                __syncthreads();
            }

            if (k0 + 16 < NXX) {
                for (int c = k0 + 16 + tid; c < NXX; c += 256) {
                    float x[16];
                    #pragma unroll
                    for (int j2 = 0; j2 < 16; ++j2) {
                        float sacc = M[(size_t)(k0 + j2) * NXX + c];
                        #pragma unroll
                        for (int i2 = 0; i2 < 16; ++i2)
                            if (i2 < j2) sacc -= P[j2 * 17 + i2] * x[i2];
                        x[j2] = sacc;
                    }
                    #pragma unroll
                    for (int j2 = 0; j2 < 16; ++j2)
                        M[(size_t)(k0 + j2) * NXX + c] = x[j2];
                }
                __syncthreads();

                for (int cbs = k0 + 16; cbs < NXX; cbs += 256) {
                    const int c = cbs + 4 * (tid & 63);
                    if (c < NXX && (c - cbs) < 256) {
                        float4 u[16];
                        #pragma unroll
                        for (int j2 = 0; j2 < 16; ++j2)
                            u[j2] = *reinterpret_cast<const float4*>(
                                &M[(size_t)(k0 + j2) * NXX + c]);
                        for (int i = k0 + 16 + (tid >> 6); i < NXX; i += 4) {
                            float4 a = *reinterpret_cast<float4*>(&M[(size_t)i * NXX + c]);
                            #pragma unroll
                            for (int j2 = 0; j2 < 16; ++j2) {
                                float l = P[(i - k0) * 17 + j2];
                                a.x -= l * u[j2].x; a.y -= l * u[j2].y;
                                a.z -= l * u[j2].z; a.w -= l * u[j2].w;
                            }
                            *reinterpret_cast<float4*>(&M[(size_t)i * NXX + c]) = a;
                        }
                    }
                }
                __syncthreads();
            }
            __syncthreads();
        }

        if (tid == 0) s_logsum = logsum;
        __syncthreads();
        logdet[tid] = (float)NTT * s_logsum;
        return;
    }

    // ============================ GEMM path =============================
    const int gb = blockIdx.x - 1;                  // 0..4095
    const int wk = (gb & 7) * 512 + (gb >> 3);      // XCD-chunked swizzle
    const int b  = wk >> 4;                         // sample
    const int tm = (wk >> 2) & 3;                   // row tile
    const int tn = wk & 3;                          // col tile
    const int t0v = T0[b];
    const int sh = t0v & 7, qv = t0v >> 3;          // T0 = 8*qv + sh

    _Float16* As_hi = (_Float16*)smem_raw;          // [4 kg][128 m][8]
    _Float16* As_lo = As_hi + 4096;
    _Float16* Bs_hi = As_lo + 4096;                 // [4 kg][128 n][8]
    _Float16* Bs_lo = Bs_hi + 4096;

    const float* Ab = phi + ((size_t)b * NTT + (size_t)tm * 128) * NXX;
    const int cb = tn * 128;

    const int w = tid >> 6, lane = tid & 63;
    const int wr = w >> 1, wc = w & 1;              // wave's 64x64 quadrant
    const int lrow = lane & 15, lkg = lane >> 4;

    const int am  = tid >> 3;                       // staging row 0..31
    const int akq = tid & 7;                        // float4 slot in 32-k
    const int akg = akq >> 1;
    const int ash = (akq & 1) * 4;

    f4 acc[4][4];
    #pragma unroll
    for (int i = 0; i < 4; ++i)
        #pragma unroll
        for (int j = 0; j < 4; ++j) {
            acc[i][j][0] = 0.f; acc[i][j][1] = 0.f;
            acc[i][j][2] = 0.f; acc[i][j][3] = 0.f;
        }

    for (int kt = 0; kt < NXX / 32; ++kt) {
        const int k0 = kt * 32;

        // ---- B stage: global_load_lds from Wtd tables (wave-uniform LDS
        //      base, lane*16B fan-out; per-lane global source address).
        //      Chunk start wrapped mod 512 at 8-elem granularity (<=504).
        #pragma unroll
        for (int i = 0; i < 2; ++i) {
            const int chunk = w * 64 + lane + i * 256;     // [kg][n] linear
            const int kg = chunk >> 7, n = chunk & 127;
            const int ustart = (k0 + 8 * (kg + qv)) & (NXX - 1);
            const size_t srow = ((size_t)(sh * NXX + cb + n)) * 512
                              + (size_t)ustart;
            gload_lds16(Whi + srow, Bs_hi + (size_t)(w * 64 + i * 256) * 8);
            gload_lds16(Wlo + srow, Bs_lo + (size_t)(w * 64 + i * 256) * 8);
        }

        // ---- A stage: fp32 load -> split hi/lo -> LDS
        float4 av[4];
        #pragma unroll
        for (int i = 0; i < 4; ++i)
            av[i] = *reinterpret_cast<const float4*>(
                Ab + (size_t)(am + 32 * i) * NXX + k0 + 4 * akq);
        #pragma unroll
        for (int i = 0; i < 4; ++i) {
            h4 hv, lv;
            const float* fx = reinterpret_cast<const float*>(&av[i]);
            #pragma unroll
            for (int j = 0; j < 4; ++j) {
                _Float16 h = (_Float16)fx[j];
                hv[j] = h;
                lv[j] = (_Float16)(fx[j] - (float)h);
            }
            const size_t base = ((size_t)akg * 128 + (am + 32 * i)) * 8 + ash;
            *(h4*)(As_hi + base) = hv;
            *(h4*)(As_lo + base) = lv;
        }
        __syncthreads();   // drains vmcnt (global_load_lds) + lgkm before reads

        // ---- compute: 16 ds_read_b128 + 48 MFMA per wave
        h8 ah[4], al[4], bh[4], bl[4];
        #pragma unroll
        for (int m = 0; m < 4; ++m) {
            const size_t ai = ((size_t)lkg * 128 + wr * 64 + m * 16 + lrow) * 8;
            ah[m] = *(const h8*)(As_hi + ai);
            al[m] = *(const h8*)(As_lo + ai);
        }
        #pragma unroll
        for (int n = 0; n < 4; ++n) {
            const size_t bi = ((size_t)lkg * 128 + wc * 64 + n * 16 + lrow) * 8;
            bh[n] = *(const h8*)(Bs_hi + bi);
            bl[n] = *(const h8*)(Bs_lo + bi);
        }
        #pragma unroll
        for (int m = 0; m < 4; ++m)
            #pragma unroll
            for (int n = 0; n < 4; ++n) {
                acc[m][n] = __builtin_amdgcn_mfma_f32_16x16x32_f16(ah[m], bh[n], acc[m][n], 0, 0, 0);
                acc[m][n] = __builtin_amdgcn_mfma_f32_16x16x32_f16(ah[m], bl[n], acc[m][n], 0, 0, 0);
                acc[m][n] = __builtin_amdgcn_mfma_f32_16x16x32_f16(al[m], bh[n], acc[m][n], 0, 0, 0);
            }
        __syncthreads();   // everyone done reading before next stage
    }

    // ---- epilogue: C/D layout col=lane&15, row=(lane>>4)*4+reg (m89-verified)
    float* O = out + (size_t)b * NTT * NXX;
    const int rbase = tm * 128 + wr * 64;
    const int cbase = cb + wc * 64;
    #pragma unroll
    for (int m = 0; m < 4; ++m) {
        #pragma unroll
        for (int r = 0; r < 4; ++r) {
            const int trow = rbase + m * 16 + lkg * 4 + r;
            const int orow = (trow - t0v + NTT) & (NTT - 1);
            float* Orow = O + (size_t)orow * NXX;
            #pragma unroll
            for (int n = 0; n < 4; ++n)
                Orow[cbase + n * 16 + lrow] = acc[m][n][r];
        }
    }
}

// ---------------------------------------------------------------------------
extern "C" void kernel_launch(void* const* d_in, const int* in_sizes, int n_in,
                              void* d_out, int out_size, void* d_ws, size_t ws_size,
                              hipStream_t stream) {
    const float* phi = reinterpret_cast<const float*>(d_in[0]);
    const float* W   = reinterpret_cast<const float*>(d_in[1]);
    float* out    = reinterpret_cast<float*>(d_out);
    float* logdet = out + (size_t)NSAMP * NTT * NXX;

    // workspace layout: T0 (1 KB) | M (1 MB) | Whi (4 MB) | Wlo (4 MB)
    char* ws = reinterpret_cast<char*>(d_ws);
    int*      T0  = reinterpret_cast<int*>(ws);
    float*    M   = reinterpret_cast<float*>(ws + 1024);
    _Float16* Whi = reinterpret_cast<_Float16*>(ws + 1024 + (1u << 20));
    _Float16* Wlo = reinterpret_cast<_Float16*>(ws + 1024 + (1u << 20) + (4u << 20));

    k_t0  <<<NSAMP, 64,  0, stream>>>(phi, T0);
    k_prep<<<NXX,   256, 0, stream>>>(W, Whi, Wlo);
    k_main<<<4097,  256, 0, stream>>>(phi, Whi, Wlo, T0, out, logdet, W, M);
}